// Round 11
// baseline (263.669 us; speedup 1.0000x reference)
//
#include <hip/hip_runtime.h>
#include <math.h>

#define NB      512
#define NELEC   30
#define NATOMS  10
#define NNEN    40      // en graph nodes: 30 electrons + 10 atoms
#define FEAT    64
#define KRBF    64
#define NPEE    435     // unique elec-elec pairs
#define NPEN    300     // unique elec-nuc pairs
#define TILE    32      // feature tile per filter thread (pair-half)
#define BLOCK   1024
#define NWAVES  16

// triangular pair index base for row i (i<j pairs of 30 electrons)
__device__ __forceinline__ int ee_base(int i) { return 29*i - ((i*(i-1))>>1); }

// Pin all 32 accumulator values into live VGPRs at this program point.
// Two statements because one asm caps at 30 operands. Forces the allocator
// to keep the full facc[] live per k-iteration -> f-tiling (R10: VGPR=32,
// two k-sweeps with duplicated exp chains) loses its register benefit.
__device__ __forceinline__ void pin32(float* a)
{
    asm volatile("" : "+v"(a[0]), "+v"(a[1]), "+v"(a[2]), "+v"(a[3]),
                      "+v"(a[4]), "+v"(a[5]), "+v"(a[6]), "+v"(a[7]),
                      "+v"(a[8]), "+v"(a[9]), "+v"(a[10]), "+v"(a[11]),
                      "+v"(a[12]), "+v"(a[13]), "+v"(a[14]), "+v"(a[15]));
    asm volatile("" : "+v"(a[16]), "+v"(a[17]), "+v"(a[18]), "+v"(a[19]),
                      "+v"(a[20]), "+v"(a[21]), "+v"(a[22]), "+v"(a[23]),
                      "+v"(a[24]), "+v"(a[25]), "+v"(a[26]), "+v"(a[27]),
                      "+v"(a[28]), "+v"(a[29]), "+v"(a[30]), "+v"(a[31]));
}

// ==========================================================================
// RBF filter core (fallback version, R7-identical): writes tanh'd tile to
// dst (LDS). uoff is an SGPR at all call sites -> weight rows are s_loads.
// ==========================================================================
__device__ __forceinline__ void rbf_core(float dd, const float* __restrict__ wf,
                                         const float* __restrict__ bf,
                                         int uoff, float* __restrict__ dst)
{
    float facc[TILE];
    const float* bfH = bf + uoff;                    // uniform -> s_load
    #pragma unroll
    for (int f = 0; f < TILE; ++f) facc[f] = bfH[f];
    #pragma unroll 4
    for (int k = 0; k < KRBF; ++k) {
        const float ck = (float)((double)k * (8.0/63.0));
        const float t  = dd - ck;
        const float rk = expf(-t*t);
        const float* wrow = wf + k*FEAT + uoff;      // uniform row -> s_load
        #pragma unroll
        for (int f = 0; f < TILE; ++f) facc[f] = fmaf(rk, wrow[f], facc[f]);
    }
    #pragma unroll
    for (int ff = 0; ff < TILE; ++ff) dst[ff] = tanhf(facc[ff]);
}

// ==========================================================================
// RBF filter into registers (K1). rk pin forbids per-f recompute (R9 fix);
// pin32 each k forces full-width k-outer (R10 fix: allocator f-tiled 2x16
// at VGPR=32, re-running the exp chain twice). Value chain bit-identical.
// ==========================================================================
__device__ __forceinline__ void rbf_regs(float dd, const float* __restrict__ wf,
                                         const float* __restrict__ bf,
                                         int uoff, float* __restrict__ facc)
{
    const float* bfH = bf + uoff;
    #pragma unroll
    for (int f = 0; f < TILE; ++f) facc[f] = bfH[f];
    #pragma unroll 4
    for (int k = 0; k < KRBF; ++k) {
        const float ck = (float)((double)k * (8.0/63.0));
        const float t  = dd - ck;
        float rk = expf(-t*t);
        asm volatile("" : "+v"(rk));                 // forbid per-f recompute
        const float* wrow = wf + k*FEAT + uoff;      // uniform row -> s_load
        #pragma unroll
        for (int f = 0; f < TILE; ++f) facc[f] = fmaf(rk, wrow[f], facc[f]);
        pin32(facc);                                 // force k-outer, no f-tile
    }
    #pragma unroll
    for (int f = 0; f < TILE; ++f) facc[f] = tanhf(facc[f]);
}

// ==========================================================================
// K1: filter kernel. Zero LDS; launch_bounds(1024,8) -> VGPR cap 64,
// 2 blocks/CU co-resident. Thread = (batch, pair, half); wave-aligned
// padding keeps batch/half wave-uniform so weight rows stay s_loads.
// ==========================================================================
#define EE_PAD  448             // 2x448 ee slots (7 waves per half)
#define EN_PAD  320             // 2x320 en slots (5 waves per half)
#define SLOTS   1536            // per batch
#define K1_GRID ((NB*SLOTS)/BLOCK)   // 768

__global__ __launch_bounds__(BLOCK, 8)
void filter_kernel(const float* __restrict__ pos,
                   const float* __restrict__ atoms,
                   const float* __restrict__ wf_ee,
                   const float* __restrict__ bf_ee,
                   const float* __restrict__ wf_en,
                   const float* __restrict__ bf_en,
                   float* __restrict__ fee,     // [NB][435][64]
                   float* __restrict__ fen)     // [NB][300][64]
{
    const int slot = blockIdx.x*BLOCK + threadIdx.x;
    const int b    = __builtin_amdgcn_readfirstlane(slot / SLOTS);
    const int r    = slot - b*SLOTS;
    const float* posB = pos + b*NELEC*3;

    float facc[TILE];
    if (r < 2*EE_PAD) {
        const int half = __builtin_amdgcn_readfirstlane(r / EE_PAD);
        const int p    = r - half*EE_PAD;
        if (p < NPEE) {
            int i = 0, rem = p;
            while (rem >= NELEC - 1 - i) { rem -= NELEC - 1 - i; ++i; }
            const int j = i + 1 + rem;
            const float dx = posB[3*i+0] - posB[3*j+0];
            const float dy = posB[3*i+1] - posB[3*j+1];
            const float dz = posB[3*i+2] - posB[3*j+2];
            const float dd = sqrtf(dx*dx + dy*dy + dz*dz);
            rbf_regs(dd, wf_ee, bf_ee, half*TILE, facc);
            float4* dst = reinterpret_cast<float4*>(
                fee + ((size_t)b*NPEE + p)*FEAT + half*TILE);
            #pragma unroll
            for (int v = 0; v < TILE/4; ++v)
                dst[v] = make_float4(facc[4*v+0], facc[4*v+1],
                                     facc[4*v+2], facc[4*v+3]);
        }
    } else {
        const int r2   = r - 2*EE_PAD;
        const int half = __builtin_amdgcn_readfirstlane(r2 / EN_PAD);
        const int p    = r2 - half*EN_PAD;
        if (p < NPEN) {
            const int a = p / NELEC;
            const int e = p - a*NELEC;
            const float dx = posB[3*e+0] - atoms[3*a+0];
            const float dy = posB[3*e+1] - atoms[3*a+1];
            const float dz = posB[3*e+2] - atoms[3*a+2];
            const float dd = sqrtf(dx*dx + dy*dy + dz*dz);
            rbf_regs(dd, wf_en, bf_en, half*TILE, facc);
            float4* dst = reinterpret_cast<float4*>(
                fen + ((size_t)b*NPEN + p)*FEAT + half*TILE);
            #pragma unroll
            for (int v = 0; v < TILE/4; ++v)
                dst[v] = make_float4(facc[4*v+0], facc[4*v+1],
                                     facc[4*v+2], facc[4*v+3]);
        }
    }
}

// ==========================================================================
// K2 helpers. Msg loops read filt rows DIRECTLY from global (the R10 fT
// staging was an identity copy whose only effect was a 111 KB LDS buffer
// capping occupancy at 1 block/CU). Reads are perfectly coalesced (lane =
// feature, 256 B/row); 29 independent loads pipeline per node; re-reads
// served by L2. FP chains identical to all passing rounds.
// ==========================================================================
__device__ __forceinline__ void ee_msg(const float* __restrict__ hc,
                                       float* __restrict__ agg,
                                       const float* __restrict__ fG,
                                       int w, int lane)
{
    for (int i = w; i < NELEC; i += NWAVES) {
        const int iu = __builtin_amdgcn_readfirstlane(i);
        float a = 0.f;
        #pragma unroll
        for (int j = 0; j < NELEC; ++j) {
            if (j != iu) {
                int pp = (j < iu) ? (ee_base(j) + (iu - j - 1))
                                  : (ee_base(iu) + (j - iu - 1));
                a = fmaf(hc[j*FEAT + lane], fG[pp*FEAT + lane], a);
            }
        }
        agg[iu*FEAT + lane] = a;
    }
}

__device__ __forceinline__ void en_msg(const float* __restrict__ hc,
                                       float* __restrict__ agg,
                                       const float* __restrict__ fG,
                                       int w, int lane)
{
    for (int n = w; n < NNEN; n += NWAVES) {
        const int nu = __builtin_amdgcn_readfirstlane(n);
        float a = 0.f;
        if (nu < NELEC) {            // electron node: atoms ascending
            #pragma unroll
            for (int at = 0; at < NATOMS; ++at)
                a = fmaf(hc[(NELEC+at)*FEAT + lane],
                         fG[(at*NELEC + nu)*FEAT + lane], a);
        } else {                     // atom node: electrons ascending
            const int at = nu - NELEC;
            #pragma unroll
            for (int e2 = 0; e2 < NELEC; ++e2)
                a = fmaf(hc[e2*FEAT + lane],
                         fG[(at*NELEC + e2)*FEAT + lane], a);
        }
        agg[nu*FEAT + lane] = a;
    }
}

__device__ __forceinline__ void dense_lds(const float* __restrict__ agg,
                                          const float* __restrict__ hc,
                                          float* __restrict__ hn,
                                          const float* __restrict__ wlS,
                                          const float* __restrict__ blL,
                                          int N, int w, int lane)
{
    for (int i = w; i < N; i += NWAVES) {
        const int iu = __builtin_amdgcn_readfirstlane(i);
        float a2 = 0.f;
        const float4* arow = reinterpret_cast<const float4*>(agg + iu*FEAT);
        #pragma unroll
        for (int k = 0; k < FEAT/4; ++k) {
            float4 av = arow[k];                     // uniform -> LDS broadcast
            a2 = fmaf(av.x, wlS[(4*k+0)*FEAT + lane], a2);
            a2 = fmaf(av.y, wlS[(4*k+1)*FEAT + lane], a2);
            a2 = fmaf(av.z, wlS[(4*k+2)*FEAT + lane], a2);
            a2 = fmaf(av.w, wlS[(4*k+3)*FEAT + lane], a2);
        }
        hn[iu*FEAT + lane] = hc[iu*FEAT + lane] + tanhf(a2 + blL[lane]);
    }
}

// ==========================================================================
// K2: layers kernel. One block per batch. LDS = kee | h0 | h1 | agg | wlS
// = 47120 B -> 2 blocks/CU (32 waves/CU). filt read from workspace in the
// msg loops; dense weights staged per layer (reused 30-40x from LDS).
// ==========================================================================
#define L2_KEE 0
#define L2_H0  4
#define L2_H1  (L2_H0 + NNEN*FEAT)      // 2564
#define L2_AGG (L2_H1 + NNEN*FEAT)      // 5124
#define L2_WLS (L2_AGG + NNEN*FEAT)     // 7684 (byte 30736, 16B aligned)
#define L2_TOT (L2_WLS + FEAT*FEAT)     // 11780 floats = 47120 B

__global__ __launch_bounds__(BLOCK)
void layers_kernel(const float* __restrict__ emb_ee,
                   const float* __restrict__ wl_ee,
                   const float* __restrict__ bl_ee,
                   const float* __restrict__ wr_ee,
                   const float* __restrict__ br_ee,
                   const float* __restrict__ emb_en,
                   const float* __restrict__ wl_en,
                   const float* __restrict__ bl_en,
                   const float* __restrict__ wr_en,
                   const float* __restrict__ br_en,
                   const int*   __restrict__ ee_ty,
                   const int*   __restrict__ en_ty,
                   const float* __restrict__ fee,
                   const float* __restrict__ fen,
                   float*       __restrict__ out)
{
    extern __shared__ float sm[];
    double* keeP = reinterpret_cast<double*>(sm + L2_KEE);
    float*  h0   = sm + L2_H0;
    float*  h1   = sm + L2_H1;
    float*  agg  = sm + L2_AGG;
    float*  wlS  = sm + L2_WLS;      // [64][64] current layer's dense weights

    const int tid  = threadIdx.x;
    const int b    = blockIdx.x;
    const int lane = tid & 63;
    const int w    = tid >> 6;

    const float* feeB = fee + (size_t)b*NPEE*FEAT;
    const float* fenB = fen + (size_t)b*NPEN*FEAT;

    // ---- S0: ee h0-init ----
    for (int idx = tid; idx < NELEC*FEAT; idx += BLOCK)
        h0[idx] = emb_ee[ee_ty[idx >> 6]*FEAT + (idx & 63)];
    __syncthreads();

    // ---- ee layer 0: {stage wl0 || msg} bar {dense} bar ----
    reinterpret_cast<float4*>(wlS)[tid] =
        reinterpret_cast<const float4*>(wl_ee)[tid];
    ee_msg(h0, agg, feeB, w, lane);
    __syncthreads();
    dense_lds(agg, h0, h1, wlS, bl_ee, NELEC, w, lane);
    __syncthreads();

    // ---- ee layer 1 ----
    reinterpret_cast<float4*>(wlS)[tid] =
        reinterpret_cast<const float4*>(wl_ee + FEAT*FEAT)[tid];
    ee_msg(h1, agg, feeB, w, lane);
    __syncthreads();
    dense_lds(agg, h1, h0, wlS, bl_ee + FEAT, NELEC, w, lane);
    __syncthreads();

    // ---- S3: ee readout (w15, h0) || en h1-init ----
    for (int idx = tid; idx < NNEN*FEAT; idx += BLOCK)
        h1[idx] = emb_en[en_ty[idx >> 6]*FEAT + (idx & 63)];
    if (w == 15) {   // kee = (sum_n h0[n]) . wr + br  (f64 tail)
        float s = 0.f;
        #pragma unroll
        for (int n = 0; n < NELEC; ++n) s += h0[n*FEAT + lane];
        double dv = (double)s * (double)wr_ee[lane];
        #pragma unroll
        for (int o = 32; o > 0; o >>= 1) dv += __shfl_xor(dv, o, 64);
        if (lane == 0) *keeP = dv + (double)br_ee[0];
    }
    __syncthreads();

    // ---- en layer 0 ----
    reinterpret_cast<float4*>(wlS)[tid] =
        reinterpret_cast<const float4*>(wl_en)[tid];
    en_msg(h1, agg, fenB, w, lane);
    __syncthreads();
    dense_lds(agg, h1, h0, wlS, bl_en, NNEN, w, lane);
    __syncthreads();

    // ---- en layer 1 ----
    reinterpret_cast<float4*>(wlS)[tid] =
        reinterpret_cast<const float4*>(wl_en + FEAT*FEAT)[tid];
    en_msg(h0, agg, fenB, w, lane);
    __syncthreads();
    dense_lds(agg, h0, h1, wlS, bl_en + FEAT, NNEN, w, lane);
    __syncthreads();

    // ---- final readout + combine ----
    if (w == 0) {
        float s = 0.f;
        #pragma unroll
        for (int n = 0; n < NNEN; ++n) s += h1[n*FEAT + lane];
        double dv = (double)s * (double)wr_en[lane];
        #pragma unroll
        for (int o = 32; o > 0; o >>= 1) dv += __shfl_xor(dv, o, 64);
        if (lane == 0) out[b] = (float)exp(dv + (double)br_en[0] + *keeP);
    }
}

// ==========================================================================
// Fallback fused kernel (R7 verbatim, 132 us) + its template layers —
// used when the workspace can't hold the 96.3 MB filt buffers.
// ==========================================================================
template<int FP>
__device__ __forceinline__ void ee_layer(const float* __restrict__ hc,
                                         float* __restrict__ hn,
                                         const float* __restrict__ filt,
                                         float* __restrict__ wr,
                                         const float* __restrict__ wlL,
                                         const float* __restrict__ blL,
                                         int w, int lane)
{
    for (int i = w; i < NELEC; i += NWAVES) {
        const int iu = __builtin_amdgcn_readfirstlane(i);
        float a = 0.f;
        #pragma unroll
        for (int j = 0; j < NELEC; ++j) {
            if (j != iu) {
                int pp = (j < iu) ? (ee_base(j) + (iu - j - 1))
                                  : (ee_base(iu) + (j - iu - 1));
                a = fmaf(hc[j*FEAT + lane], filt[pp*FP + lane], a);
            }
        }
        wr[lane] = a;
        float a2 = 0.f;
        const float4* arow = reinterpret_cast<const float4*>(wr);
        #pragma unroll
        for (int k = 0; k < FEAT/4; ++k) {
            float4 av = arow[k];
            a2 = fmaf(av.x, wlL[(4*k+0)*FEAT + lane], a2);
            a2 = fmaf(av.y, wlL[(4*k+1)*FEAT + lane], a2);
            a2 = fmaf(av.z, wlL[(4*k+2)*FEAT + lane], a2);
            a2 = fmaf(av.w, wlL[(4*k+3)*FEAT + lane], a2);
        }
        hn[iu*FEAT + lane] = hc[iu*FEAT + lane] + tanhf(a2 + blL[lane]);
    }
}

template<int FP>
__device__ __forceinline__ void en_layer(const float* __restrict__ hc,
                                         float* __restrict__ hn,
                                         const float* __restrict__ filt,
                                         float* __restrict__ wr,
                                         const float* __restrict__ wlL,
                                         const float* __restrict__ blL,
                                         int w, int lane)
{
    for (int n = w; n < NNEN; n += NWAVES) {
        const int nu = __builtin_amdgcn_readfirstlane(n);
        float a = 0.f;
        if (nu < NELEC) {
            #pragma unroll
            for (int at = 0; at < NATOMS; ++at)
                a = fmaf(hc[(NELEC+at)*FEAT + lane],
                         filt[(at*NELEC + nu)*FP + lane], a);
        } else {
            const int at = nu - NELEC;
            #pragma unroll
            for (int e2 = 0; e2 < NELEC; ++e2)
                a = fmaf(hc[e2*FEAT + lane],
                         filt[(at*NELEC + e2)*FP + lane], a);
        }
        wr[lane] = a;
        float a2 = 0.f;
        const float4* arow = reinterpret_cast<const float4*>(wr);
        #pragma unroll
        for (int k = 0; k < FEAT/4; ++k) {
            float4 av = arow[k];
            a2 = fmaf(av.x, wlL[(4*k+0)*FEAT + lane], a2);
            a2 = fmaf(av.y, wlL[(4*k+1)*FEAT + lane], a2);
            a2 = fmaf(av.z, wlL[(4*k+2)*FEAT + lane], a2);
            a2 = fmaf(av.w, wlL[(4*k+3)*FEAT + lane], a2);
        }
        hn[nu*FEAT + lane] = hc[nu*FEAT + lane] + tanhf(a2 + blL[lane]);
    }
}

#define FB_FPAD  65
#define FB_KEE   0
#define FB_H0    4
#define FB_H1    (FB_H0 + NNEN*FEAT)       // 2564
#define FB_FILT  (FB_H1 + NNEN*FEAT)       // 5124
#define FB_WR    33400                     // 5124 + 435*65 = 33399, +1 align
#define FB_TOT   (FB_WR + NWAVES*64)       // 34424 floats = 137696 B

__global__ __launch_bounds__(BLOCK)
void fused_kernel(const float* __restrict__ pos,
                  const float* __restrict__ atoms,
                  const float* __restrict__ emb_ee,
                  const float* __restrict__ wf_ee,
                  const float* __restrict__ bf_ee,
                  const float* __restrict__ wl_ee,
                  const float* __restrict__ bl_ee,
                  const float* __restrict__ wr_ee,
                  const float* __restrict__ br_ee,
                  const float* __restrict__ emb_en,
                  const float* __restrict__ wf_en,
                  const float* __restrict__ bf_en,
                  const float* __restrict__ wl_en,
                  const float* __restrict__ bl_en,
                  const float* __restrict__ wr_en,
                  const float* __restrict__ br_en,
                  const int*   __restrict__ ee_ty,
                  const int*   __restrict__ en_ty,
                  float*       __restrict__ out)
{
    extern __shared__ float sm[];
    double* keeP = reinterpret_cast<double*>(sm + FB_KEE);
    float*  h0   = sm + FB_H0;
    float*  h1   = sm + FB_H1;
    float*  filt = sm + FB_FILT;
    float*  wrS  = sm + FB_WR;

    const int tid  = threadIdx.x;
    const int b    = blockIdx.x;
    const int lane = tid & 63;
    const int w    = tid >> 6;
    float* wr = wrS + w*64;
    const float* posB = pos + b*NELEC*3;

    const int  ee_t   = (w >= 7) ? 1 : 0;
    const int  ee_p   = ((w >= 7 ? w - 7 : w) << 6) | lane;
    const bool ee_ok  = (w < 14) && (ee_p < NPEE);
    const int  v      = w & 7;
    const int  en_blk = (w < 8) ? (v < 5 ? v : -1)
                                : ((v >= 1 && v <= 3) ? v - 1
                                   : (v == 5 || v == 6) ? v - 2 : -1);
    const int  en_t   = (w >= 8) ? 1 : 0;
    const int  en_p   = (en_blk < 0) ? 0 : ((en_blk << 6) | lane);
    const bool en_ok  = (en_blk >= 0) && (en_p < NPEN);
    const int  hr     = (w == 5) ? 0 : (w == 6) ? 1 : (w == 7) ? 2
                      : (w == 8) ? 3 : (w == 12) ? 4 : -1;
    const int uoff_ee = __builtin_amdgcn_readfirstlane(ee_t * TILE);
    const int uoff_en = __builtin_amdgcn_readfirstlane(en_t * TILE);

    if (ee_ok) {
        int i = 0, rem = ee_p;
        while (rem >= NELEC - 1 - i) { rem -= NELEC - 1 - i; ++i; }
        const int j = i + 1 + rem;
        const float dx = posB[3*i+0] - posB[3*j+0];
        const float dy = posB[3*i+1] - posB[3*j+1];
        const float dz = posB[3*i+2] - posB[3*j+2];
        const float dd = sqrtf(dx*dx + dy*dy + dz*dz);
        rbf_core(dd, wf_ee, bf_ee, uoff_ee, filt + ee_p*FB_FPAD + uoff_ee);
    }
    if (w >= 14) {
        for (int idx = tid - 14*64; idx < NELEC*FEAT; idx += BLOCK - 14*64) {
            int n = idx >> 6, f = idx & 63;
            h0[idx] = emb_ee[ee_ty[n]*FEAT + f];
        }
    }
    __syncthreads();

    ee_layer<FB_FPAD>(h0, h1, filt, wr, wl_ee, bl_ee, w, lane);
    __syncthreads();
    ee_layer<FB_FPAD>(h1, h0, filt, wr, wl_ee + FEAT*FEAT, bl_ee + FEAT, w, lane);
    __syncthreads();

    if (en_ok) {
        const int a = en_p / NELEC;
        const int e = en_p - a*NELEC;
        const float dx = posB[3*e+0] - atoms[3*a+0];
        const float dy = posB[3*e+1] - atoms[3*a+1];
        const float dz = posB[3*e+2] - atoms[3*a+2];
        const float dd = sqrtf(dx*dx + dy*dy + dz*dz);
        rbf_core(dd, wf_en, bf_en, uoff_en, filt + en_p*FB_FPAD + uoff_en);
    }
    if (hr >= 0) {
        #pragma unroll
        for (int r = 0; r < 8; ++r) {
            const int idx = hr*64 + lane + r*320;
            h1[idx] = emb_en[en_ty[idx >> 6]*FEAT + (idx & 63)];
        }
    }
    if (w == 15) {
        float s = 0.f;
        #pragma unroll
        for (int n = 0; n < NELEC; ++n) s += h0[n*FEAT + lane];
        double dv = (double)s * (double)wr_ee[lane];
        #pragma unroll
        for (int o = 32; o > 0; o >>= 1) dv += __shfl_xor(dv, o, 64);
        if (lane == 0) *keeP = dv + (double)br_ee[0];
    }
    __syncthreads();

    en_layer<FB_FPAD>(h1, h0, filt, wr, wl_en, bl_en, w, lane);
    __syncthreads();
    en_layer<FB_FPAD>(h0, h1, filt, wr, wl_en + FEAT*FEAT, bl_en + FEAT, w, lane);
    __syncthreads();

    if (w == 0) {
        float s = 0.f;
        #pragma unroll
        for (int n = 0; n < NNEN; ++n) s += h1[n*FEAT + lane];
        double dv = (double)s * (double)wr_en[lane];
        #pragma unroll
        for (int o = 32; o > 0; o >>= 1) dv += __shfl_xor(dv, o, 64);
        if (lane == 0) out[b] = (float)exp(dv + (double)br_en[0] + *keeP);
    }
}

// ==========================================================================
extern "C" void kernel_launch(void* const* d_in, const int* in_sizes, int n_in,
                              void* d_out, int out_size, void* d_ws, size_t ws_size,
                              hipStream_t stream) {
    const float* pos    = (const float*)d_in[0];
    const float* atoms  = (const float*)d_in[1];
    const float* emb_ee = (const float*)d_in[2];
    const float* wf_ee  = (const float*)d_in[3];
    const float* bf_ee  = (const float*)d_in[4];
    const float* wl_ee  = (const float*)d_in[5];
    const float* bl_ee  = (const float*)d_in[6];
    const float* wr_ee  = (const float*)d_in[7];
    const float* br_ee  = (const float*)d_in[8];
    const float* emb_en = (const float*)d_in[9];
    const float* wf_en  = (const float*)d_in[10];
    const float* bf_en  = (const float*)d_in[11];
    const float* wl_en  = (const float*)d_in[12];
    const float* bl_en  = (const float*)d_in[13];
    const float* wr_en  = (const float*)d_in[14];
    const float* br_en  = (const float*)d_in[15];
    const int*   ee_ty  = (const int*)d_in[18];
    const int*   en_ty  = (const int*)d_in[21];

    float* out = (float*)d_out;        // [512]

    const size_t need = (size_t)NB * (NPEE + NPEN) * FEAT * sizeof(float); // 96.3 MB

    if (d_ws != nullptr && ws_size >= need) {
        float* fee = (float*)d_ws;                         // [512][435][64]
        float* fen = fee + (size_t)NB * NPEE * FEAT;       // [512][300][64]

        filter_kernel<<<K1_GRID, BLOCK, 0, stream>>>(
            pos, atoms, wf_ee, bf_ee, wf_en, bf_en, fee, fen);

        (void)hipFuncSetAttribute((const void*)layers_kernel,
                hipFuncAttributeMaxDynamicSharedMemorySize, L2_TOT*(int)sizeof(float));
        layers_kernel<<<NB, BLOCK, L2_TOT*sizeof(float), stream>>>(
            emb_ee, wl_ee, bl_ee, wr_ee, br_ee,
            emb_en, wl_en, bl_en, wr_en, br_en,
            ee_ty, en_ty, fee, fen, out);
    } else {
        (void)hipFuncSetAttribute((const void*)fused_kernel,
                hipFuncAttributeMaxDynamicSharedMemorySize, FB_TOT*(int)sizeof(float));
        fused_kernel<<<NB, BLOCK, FB_TOT*sizeof(float), stream>>>(
            pos, atoms,
            emb_ee, wf_ee, bf_ee, wl_ee, bl_ee, wr_ee, br_ee,
            emb_en, wf_en, bf_en, wl_en, bl_en, wr_en, br_en,
            ee_ty, en_ty, out);
    }
}

// Round 12
// 198.317 us; speedup vs baseline: 1.3295x; 1.3295x over previous
//
#include <hip/hip_runtime.h>
#include <math.h>

#define NB      512
#define NELEC   30
#define NATOMS  10
#define NNEN    40      // en graph nodes: 30 electrons + 10 atoms
#define FEAT    64
#define KRBF    64
#define BLOCK   1024
#define NWAVES  16
#define NPEE    435     // unique elec-elec pairs
#define NPEN    300     // unique elec-nuc pairs
#define TILE    32      // feature tile per filter thread (pair-half)
#define FPAD    65      // filt row stride (+1): lanes hit banks (p+f)%32, 2-way = free

// ---------------- LDS layout (floats) ----------------
// kee(double)@0 | h0[40][64] | h1[40][64] | filt[435][65] | wrS[16][64]
#define OFF_KEE   0                         // byte 0, 8B-aligned
#define H0_OFF    4
#define H1_OFF    (H0_OFF + NNEN*FEAT)      // 2564
#define FILT_OFF  (H1_OFF + NNEN*FEAT)      // 5124
#define WR_ALN    33400                     // 5124 + 435*65 = 33399, +1 align 16B
#define SM_TOTAL  (WR_ALN + NWAVES*64)      // 34424 fl = 137696 B -> 1 block/CU

// triangular pair index base for row i (i<j pairs of 30 electrons)
__device__ __forceinline__ int ee_base(int i) { return 29*i - ((i*(i-1))>>1); }

// ==========================================================================
// RBF filter. R12 change (the ONLY change vs the 132 us R7 kernel):
// expf(-t*t) -> __builtin_amdgcn_exp2f(-log2e * t*t), i.e. the raw
// v_exp_f32 transcendental. exp(x) = exp2(x*log2e) exactly in infinite
// precision; the single-multiply form costs ~1-2 ulp vs ocml expf's ~25-30
// VALU-op libm sequence. Instruction-budget audit (R11): the filter phases
// are ~60% of issue and expf's sequence is their dominant term — 3 ops vs
// ~25-30 per call, 24M+ calls. First deliberate bit-inexactness of the
// session; predicted absmax <= 1e-4 on O(1) outputs.
// Everything else (k order, fma chain, tanhf, f64 readout) is unchanged.
// ==========================================================================
__device__ __forceinline__ void rbf_filter(float dd, const float* __restrict__ wf,
                                           const float* __restrict__ bf,
                                           int uoff, float* __restrict__ dstrow)
{
    float facc[TILE];
    const float* bfH = bf + uoff;                    // uniform -> s_load
    #pragma unroll
    for (int f = 0; f < TILE; ++f) facc[f] = bfH[f];
    #pragma unroll 4
    for (int k = 0; k < KRBF; ++k) {
        const float ck = (float)((double)k * (8.0/63.0));
        const float t  = dd - ck;
        const float rk = __builtin_amdgcn_exp2f(-1.44269504088896340736f * (t*t));
        const float* wrow = wf + k*FEAT + uoff;      // uniform row -> s_load
        #pragma unroll
        for (int f = 0; f < TILE; ++f) facc[f] = fmaf(rk, wrow[f], facc[f]);
    }
    #pragma unroll
    for (int ff = 0; ff < TILE; ++ff) dstrow[uoff + ff] = tanhf(facc[ff]);
}

// ==========================================================================
// Fused per-wave ee layer: wave = node, lane = feature.
// iu = readfirstlane(i) -> pair-index/row-base arithmetic on SALU.
// Message sum -> private LDS row roundtrip (same-wave, lgkmcnt only) ->
// float4-broadcast dense -> hn. One barrier per layer (caller).
// ==========================================================================
__device__ __forceinline__ void ee_layer(const float* __restrict__ hc,
                                         float* __restrict__ hn,
                                         const float* __restrict__ filt,
                                         float* __restrict__ wr,
                                         const float* __restrict__ wlL,
                                         const float* __restrict__ blL,
                                         int w, int lane)
{
    for (int i = w; i < NELEC; i += NWAVES) {
        const int iu = __builtin_amdgcn_readfirstlane(i);   // SALU addressing
        float a = 0.f;
        #pragma unroll
        for (int j = 0; j < NELEC; ++j) {
            if (j != iu) {
                int pp = (j < iu) ? (ee_base(j) + (iu - j - 1))
                                  : (ee_base(iu) + (j - iu - 1));
                a = fmaf(hc[j*FEAT + lane], filt[pp*FPAD + lane], a);
            }
        }
        wr[lane] = a;                         // same-wave roundtrip
        float a2 = 0.f;
        const float4* arow = reinterpret_cast<const float4*>(wr);
        #pragma unroll
        for (int k = 0; k < FEAT/4; ++k) {
            float4 av = arow[k];              // uniform -> LDS broadcast b128
            a2 = fmaf(av.x, wlL[(4*k+0)*FEAT + lane], a2);
            a2 = fmaf(av.y, wlL[(4*k+1)*FEAT + lane], a2);
            a2 = fmaf(av.z, wlL[(4*k+2)*FEAT + lane], a2);
            a2 = fmaf(av.w, wlL[(4*k+3)*FEAT + lane], a2);
        }
        hn[iu*FEAT + lane] = hc[iu*FEAT + lane] + tanhf(a2 + blL[lane]);
    }
}

__device__ __forceinline__ void en_layer(const float* __restrict__ hc,
                                         float* __restrict__ hn,
                                         const float* __restrict__ filt,
                                         float* __restrict__ wr,
                                         const float* __restrict__ wlL,
                                         const float* __restrict__ blL,
                                         int w, int lane)
{
    for (int n = w; n < NNEN; n += NWAVES) {
        const int nu = __builtin_amdgcn_readfirstlane(n);
        float a = 0.f;
        if (nu < NELEC) {            // scalar branch: electron node, atoms asc
            #pragma unroll
            for (int at = 0; at < NATOMS; ++at)
                a = fmaf(hc[(NELEC+at)*FEAT + lane],
                         filt[(at*NELEC + nu)*FPAD + lane], a);
        } else {                     // atom node: electrons ascending
            const int at = nu - NELEC;
            #pragma unroll
            for (int e2 = 0; e2 < NELEC; ++e2)
                a = fmaf(hc[e2*FEAT + lane],
                         filt[(at*NELEC + e2)*FPAD + lane], a);
        }
        wr[lane] = a;
        float a2 = 0.f;
        const float4* arow = reinterpret_cast<const float4*>(wr);
        #pragma unroll
        for (int k = 0; k < FEAT/4; ++k) {
            float4 av = arow[k];
            a2 = fmaf(av.x, wlL[(4*k+0)*FEAT + lane], a2);
            a2 = fmaf(av.y, wlL[(4*k+1)*FEAT + lane], a2);
            a2 = fmaf(av.z, wlL[(4*k+2)*FEAT + lane], a2);
            a2 = fmaf(av.w, wlL[(4*k+3)*FEAT + lane], a2);
        }
        hn[nu*FEAT + lane] = hc[nu*FEAT + lane] + tanhf(a2 + blL[lane]);
    }
}

// ==========================================================================
// Fused ee+en GNN (R7 structure verbatim). One block per batch.
// Segments (6 barriers):
//  S0 [w0-13: ee-filter] || [w14-15: ee h0-init]           | barrier
//  L1 ee-l0 h0->h1 | L2 ee-l1 h1->h0                       | barrier each
//  S3 [w15: ee-readout(h0)] || [en-filter waves] || [hr: en h1-init] | barrier
//  L4 en-l0 h1->h0 | L5 en-l1 h0->h1                       | barrier each
//  S6 w0: final readout(h1) + combine
// ==========================================================================
__global__ __launch_bounds__(BLOCK)
void fused_kernel(const float* __restrict__ pos,
                  const float* __restrict__ atoms,
                  const float* __restrict__ emb_ee,
                  const float* __restrict__ wf_ee,
                  const float* __restrict__ bf_ee,
                  const float* __restrict__ wl_ee,
                  const float* __restrict__ bl_ee,
                  const float* __restrict__ wr_ee,
                  const float* __restrict__ br_ee,
                  const float* __restrict__ emb_en,
                  const float* __restrict__ wf_en,
                  const float* __restrict__ bf_en,
                  const float* __restrict__ wl_en,
                  const float* __restrict__ bl_en,
                  const float* __restrict__ wr_en,
                  const float* __restrict__ br_en,
                  const int*   __restrict__ ee_ty,
                  const int*   __restrict__ en_ty,
                  float*       __restrict__ out)
{
    extern __shared__ float sm[];
    double* keeP = reinterpret_cast<double*>(sm + OFF_KEE);
    float*  h0   = sm + H0_OFF;      // [40][64]
    float*  h1   = sm + H1_OFF;      // [40][64]
    float*  filt = sm + FILT_OFF;    // [435][65]
    float*  wrS  = sm + WR_ALN;      // [16][64]

    const int tid  = threadIdx.x;
    const int b    = blockIdx.x;
    const int lane = tid & 63;
    const int w    = tid >> 6;
    float* wr = wrS + w*64;          // this wave's private agg row

    const float* posB = pos + b*NELEC*3;

    // ---- wave roles ----
    // ee filter: waves 0-13 (t = w>=7), pair = (w mod 7)*64+lane -> SIMD (4,4,3,3)
    const int  ee_t   = (w >= 7) ? 1 : 0;
    const int  ee_p   = ((w >= 7 ? w - 7 : w) << 6) | lane;
    const bool ee_ok  = (w < 14) && (ee_p < NPEE);
    // en filter: active waves {0,1,2,3,4, 9,10,11,13,14} -> SIMD (2,3,3,2)
    const int  v      = w & 7;
    const int  en_blk = (w < 8) ? (v < 5 ? v : -1)
                                : ((v >= 1 && v <= 3) ? v - 1
                                   : (v == 5 || v == 6) ? v - 2 : -1);
    const int  en_t   = (w >= 8) ? 1 : 0;
    const int  en_p   = (en_blk < 0) ? 0 : ((en_blk << 6) | lane);
    const bool en_ok  = (en_blk >= 0) && (en_p < NPEN);
    // en h-init: waves {5,6,7,8,12} (disjoint from en-filter waves and w15)
    const int  hr     = (w == 5) ? 0 : (w == 6) ? 1 : (w == 7) ? 2
                      : (w == 8) ? 3 : (w == 12) ? 4 : -1;

    const int uoff_ee = __builtin_amdgcn_readfirstlane(ee_t * TILE);
    const int uoff_en = __builtin_amdgcn_readfirstlane(en_t * TILE);

    // ---------------- S0: ee filter (w0-13) || ee h0-init (w14-15) --------
    if (ee_ok) {
        int i = 0, rem = ee_p;
        while (rem >= NELEC - 1 - i) { rem -= NELEC - 1 - i; ++i; }
        const int j = i + 1 + rem;
        const float dx = posB[3*i+0] - posB[3*j+0];
        const float dy = posB[3*i+1] - posB[3*j+1];
        const float dz = posB[3*i+2] - posB[3*j+2];
        const float dd = sqrtf(dx*dx + dy*dy + dz*dz);
        rbf_filter(dd, wf_ee, bf_ee, uoff_ee, filt + ee_p*FPAD);
    }
    if (w >= 14) {   // 128 threads init h0 (1920 items, 15 iters)
        for (int idx = tid - 14*64; idx < NELEC*FEAT; idx += 128) {
            int n = idx >> 6, f = idx & 63;
            h0[idx] = emb_ee[ee_ty[n]*FEAT + f];
        }
    }
    __syncthreads();

    // ---------------- ee interaction layers (1 barrier each) --------------
    ee_layer(h0, h1, filt, wr, wl_ee + 0*FEAT*FEAT, bl_ee + 0*FEAT, w, lane);
    __syncthreads();
    ee_layer(h1, h0, filt, wr, wl_ee + 1*FEAT*FEAT, bl_ee + 1*FEAT, w, lane);
    __syncthreads();

    // ------- S3: ee readout (w15, h0) || en filter || en h1-init ----------
    if (en_ok) {
        const int a = en_p / NELEC;
        const int e = en_p - a*NELEC;
        const float dx = posB[3*e+0] - atoms[3*a+0];
        const float dy = posB[3*e+1] - atoms[3*a+1];
        const float dz = posB[3*e+2] - atoms[3*a+2];
        const float dd = sqrtf(dx*dx + dy*dy + dz*dz);
        rbf_filter(dd, wf_en, bf_en, uoff_en, filt + en_p*FPAD);
    }
    if (hr >= 0) {   // en h -> h1 (2560 items on 5 waves, 8 iters)
        #pragma unroll
        for (int r = 0; r < 8; ++r) {
            const int idx = hr*64 + lane + r*320;
            h1[idx] = emb_en[en_ty[idx >> 6]*FEAT + (idx & 63)];
        }
    }
    if (w == 15) {   // kee = (sum_n h0[n]) . wr + br  (f64 tail)
        float s = 0.f;
        #pragma unroll
        for (int n = 0; n < NELEC; ++n) s += h0[n*FEAT + lane];
        double dv = (double)s * (double)wr_ee[lane];
        #pragma unroll
        for (int o = 32; o > 0; o >>= 1) dv += __shfl_xor(dv, o, 64);
        if (lane == 0) *keeP = dv + (double)br_ee[0];
    }
    __syncthreads();

    // ---------------- en interaction layers -------------------------------
    en_layer(h1, h0, filt, wr, wl_en + 0*FEAT*FEAT, bl_en + 0*FEAT, w, lane);
    __syncthreads();
    en_layer(h0, h1, filt, wr, wl_en + 1*FEAT*FEAT, bl_en + 1*FEAT, w, lane);
    __syncthreads();

    // ---------------- final readout + combine -----------------------------
    if (w == 0) {
        float s = 0.f;
        #pragma unroll
        for (int n = 0; n < NNEN; ++n) s += h1[n*FEAT + lane];
        double dv = (double)s * (double)wr_en[lane];
        #pragma unroll
        for (int o = 32; o > 0; o >>= 1) dv += __shfl_xor(dv, o, 64);
        if (lane == 0) out[b] = (float)exp(dv + (double)br_en[0] + *keeP);
    }
}

// ==========================================================================
extern "C" void kernel_launch(void* const* d_in, const int* in_sizes, int n_in,
                              void* d_out, int out_size, void* d_ws, size_t ws_size,
                              hipStream_t stream) {
    const float* pos    = (const float*)d_in[0];
    const float* atoms  = (const float*)d_in[1];
    const float* emb_ee = (const float*)d_in[2];
    const float* wf_ee  = (const float*)d_in[3];
    const float* bf_ee  = (const float*)d_in[4];
    const float* wl_ee  = (const float*)d_in[5];
    const float* bl_ee  = (const float*)d_in[6];
    const float* wr_ee  = (const float*)d_in[7];
    const float* br_ee  = (const float*)d_in[8];
    const float* emb_en = (const float*)d_in[9];
    const float* wf_en  = (const float*)d_in[10];
    const float* bf_en  = (const float*)d_in[11];
    const float* wl_en  = (const float*)d_in[12];
    const float* bl_en  = (const float*)d_in[13];
    const float* wr_en  = (const float*)d_in[14];
    const float* br_en  = (const float*)d_in[15];
    const int*   ee_ty  = (const int*)d_in[18];
    const int*   en_ty  = (const int*)d_in[21];

    float* out = (float*)d_out;        // [512]

    (void)hipFuncSetAttribute((const void*)fused_kernel,
            hipFuncAttributeMaxDynamicSharedMemorySize, SM_TOTAL*(int)sizeof(float));

    fused_kernel<<<NB, BLOCK, SM_TOTAL*sizeof(float), stream>>>(
        pos, atoms,
        emb_ee, wf_ee, bf_ee, wl_ee, bl_ee, wr_ee, br_ee,
        emb_en, wf_en, bf_en, wl_en, bl_en, wr_en, br_en,
        ee_ty, en_ty, out);
}

// Round 13
// 190.244 us; speedup vs baseline: 1.3860x; 1.0424x over previous
//
#include <hip/hip_runtime.h>
#include <math.h>

#define NB      512
#define NELEC   30
#define NATOMS  10
#define NNEN    40      // en graph nodes: 30 electrons + 10 atoms
#define FEAT    64
#define KRBF    64
#define BLOCK   1024
#define NWAVES  16
#define NPEE    435     // unique elec-elec pairs
#define NPEN    300     // unique elec-nuc pairs
#define TILE    32      // feature tile per filter thread (pair-half)
#define FPAD    65      // filt row stride (+1): lanes hit banks (p+f)%32, 2-way = free

// ---------------- LDS layout (floats) ----------------
// kee(double)@0 | h0[40][64] | h1[40][64] | filt[435][65] | wrS[16][64]
#define OFF_KEE   0                         // byte 0, 8B-aligned
#define H0_OFF    4
#define H1_OFF    (H0_OFF + NNEN*FEAT)      // 2564
#define FILT_OFF  (H1_OFF + NNEN*FEAT)      // 5124
#define WR_ALN    33400                     // 5124 + 435*65 = 33399, +1 align 16B
#define SM_TOTAL  (WR_ALN + NWAVES*64)      // 34424 fl = 137696 B -> 1 block/CU

// triangular pair index base for row i (i<j pairs of 30 electrons)
__device__ __forceinline__ int ee_base(int i) { return 29*i - ((i*(i-1))>>1); }

// ==========================================================================
// Fast transcendentals on the hardware pipe.
// R12 (kept): exp(-t^2) = v_exp_f32(-log2e * t^2)      — 3 ops vs ~25 libm.
// R13 (new):  tanh(x) = 1 - 2/(exp2(2*log2e*x)+1)
//             via v_exp_f32 + v_rcp_f32                 — 5 ops vs ~25 libm.
// Tails are exact: x>>0 -> u=inf -> rcp(inf)=0 -> 1; x<<0 -> u=0 -> -1.
// Mid-range error ~2-3 ulp — same risk class as R12's exp swap (absmax 0.0).
// tanhf was the largest remaining VALU term after R12 (27840 filter calls +
// 8960 layer calls per block at ~25 ops each).
// ==========================================================================
__device__ __forceinline__ float fast_tanhf(float x)
{
    const float u = __builtin_amdgcn_exp2f(2.885390081777926774f * x); // 2*log2e
    const float r = __builtin_amdgcn_rcpf(u + 1.0f);
    return fmaf(-2.0f, r, 1.0f);
}

// ==========================================================================
// RBF filter: facc = tanh(bf + sum_k exp(-(dd-ck)^2) * wf[k]), 32-feature
// half per thread; uoff is an SGPR at all call sites -> weight rows are
// wave-uniform s_loads. k order and fma chain unchanged from all passing
// rounds; transcendentals on the hardware pipe (see above).
// ==========================================================================
__device__ __forceinline__ void rbf_filter(float dd, const float* __restrict__ wf,
                                           const float* __restrict__ bf,
                                           int uoff, float* __restrict__ dstrow)
{
    float facc[TILE];
    const float* bfH = bf + uoff;                    // uniform -> s_load
    #pragma unroll
    for (int f = 0; f < TILE; ++f) facc[f] = bfH[f];
    #pragma unroll 4
    for (int k = 0; k < KRBF; ++k) {
        const float ck = (float)((double)k * (8.0/63.0));
        const float t  = dd - ck;
        const float rk = __builtin_amdgcn_exp2f(-1.44269504088896340736f * (t*t));
        const float* wrow = wf + k*FEAT + uoff;      // uniform row -> s_load
        #pragma unroll
        for (int f = 0; f < TILE; ++f) facc[f] = fmaf(rk, wrow[f], facc[f]);
    }
    #pragma unroll
    for (int ff = 0; ff < TILE; ++ff) dstrow[uoff + ff] = fast_tanhf(facc[ff]);
}

// ==========================================================================
// Fused per-wave ee layer: wave = node, lane = feature.
// iu = readfirstlane(i) -> pair-index/row-base arithmetic on SALU.
// Message sum -> private LDS row roundtrip (same-wave, lgkmcnt only) ->
// float4-broadcast dense -> hn. One barrier per layer (caller).
// ==========================================================================
__device__ __forceinline__ void ee_layer(const float* __restrict__ hc,
                                         float* __restrict__ hn,
                                         const float* __restrict__ filt,
                                         float* __restrict__ wr,
                                         const float* __restrict__ wlL,
                                         const float* __restrict__ blL,
                                         int w, int lane)
{
    for (int i = w; i < NELEC; i += NWAVES) {
        const int iu = __builtin_amdgcn_readfirstlane(i);   // SALU addressing
        float a = 0.f;
        #pragma unroll
        for (int j = 0; j < NELEC; ++j) {
            if (j != iu) {
                int pp = (j < iu) ? (ee_base(j) + (iu - j - 1))
                                  : (ee_base(iu) + (j - iu - 1));
                a = fmaf(hc[j*FEAT + lane], filt[pp*FPAD + lane], a);
            }
        }
        wr[lane] = a;                         // same-wave roundtrip
        float a2 = 0.f;
        const float4* arow = reinterpret_cast<const float4*>(wr);
        #pragma unroll
        for (int k = 0; k < FEAT/4; ++k) {
            float4 av = arow[k];              // uniform -> LDS broadcast b128
            a2 = fmaf(av.x, wlL[(4*k+0)*FEAT + lane], a2);
            a2 = fmaf(av.y, wlL[(4*k+1)*FEAT + lane], a2);
            a2 = fmaf(av.z, wlL[(4*k+2)*FEAT + lane], a2);
            a2 = fmaf(av.w, wlL[(4*k+3)*FEAT + lane], a2);
        }
        hn[iu*FEAT + lane] = hc[iu*FEAT + lane] + fast_tanhf(a2 + blL[lane]);
    }
}

__device__ __forceinline__ void en_layer(const float* __restrict__ hc,
                                         float* __restrict__ hn,
                                         const float* __restrict__ filt,
                                         float* __restrict__ wr,
                                         const float* __restrict__ wlL,
                                         const float* __restrict__ blL,
                                         int w, int lane)
{
    for (int n = w; n < NNEN; n += NWAVES) {
        const int nu = __builtin_amdgcn_readfirstlane(n);
        float a = 0.f;
        if (nu < NELEC) {            // scalar branch: electron node, atoms asc
            #pragma unroll
            for (int at = 0; at < NATOMS; ++at)
                a = fmaf(hc[(NELEC+at)*FEAT + lane],
                         filt[(at*NELEC + nu)*FPAD + lane], a);
        } else {                     // atom node: electrons ascending
            const int at = nu - NELEC;
            #pragma unroll
            for (int e2 = 0; e2 < NELEC; ++e2)
                a = fmaf(hc[e2*FEAT + lane],
                         filt[(at*NELEC + e2)*FPAD + lane], a);
        }
        wr[lane] = a;
        float a2 = 0.f;
        const float4* arow = reinterpret_cast<const float4*>(wr);
        #pragma unroll
        for (int k = 0; k < FEAT/4; ++k) {
            float4 av = arow[k];
            a2 = fmaf(av.x, wlL[(4*k+0)*FEAT + lane], a2);
            a2 = fmaf(av.y, wlL[(4*k+1)*FEAT + lane], a2);
            a2 = fmaf(av.z, wlL[(4*k+2)*FEAT + lane], a2);
            a2 = fmaf(av.w, wlL[(4*k+3)*FEAT + lane], a2);
        }
        hn[nu*FEAT + lane] = hc[nu*FEAT + lane] + fast_tanhf(a2 + blL[lane]);
    }
}

// ==========================================================================
// Fused ee+en GNN (R7 structure verbatim). One block per batch.
// Segments (6 barriers):
//  S0 [w0-13: ee-filter] || [w14-15: ee h0-init]           | barrier
//  L1 ee-l0 h0->h1 | L2 ee-l1 h1->h0                       | barrier each
//  S3 [w15: ee-readout(h0)] || [en-filter waves] || [hr: en h1-init] | barrier
//  L4 en-l0 h1->h0 | L5 en-l1 h0->h1                       | barrier each
//  S6 w0: final readout(h1) + combine
// ==========================================================================
__global__ __launch_bounds__(BLOCK)
void fused_kernel(const float* __restrict__ pos,
                  const float* __restrict__ atoms,
                  const float* __restrict__ emb_ee,
                  const float* __restrict__ wf_ee,
                  const float* __restrict__ bf_ee,
                  const float* __restrict__ wl_ee,
                  const float* __restrict__ bl_ee,
                  const float* __restrict__ wr_ee,
                  const float* __restrict__ br_ee,
                  const float* __restrict__ emb_en,
                  const float* __restrict__ wf_en,
                  const float* __restrict__ bf_en,
                  const float* __restrict__ wl_en,
                  const float* __restrict__ bl_en,
                  const float* __restrict__ wr_en,
                  const float* __restrict__ br_en,
                  const int*   __restrict__ ee_ty,
                  const int*   __restrict__ en_ty,
                  float*       __restrict__ out)
{
    extern __shared__ float sm[];
    double* keeP = reinterpret_cast<double*>(sm + OFF_KEE);
    float*  h0   = sm + H0_OFF;      // [40][64]
    float*  h1   = sm + H1_OFF;      // [40][64]
    float*  filt = sm + FILT_OFF;    // [435][65]
    float*  wrS  = sm + WR_ALN;      // [16][64]

    const int tid  = threadIdx.x;
    const int b    = blockIdx.x;
    const int lane = tid & 63;
    const int w    = tid >> 6;
    float* wr = wrS + w*64;          // this wave's private agg row

    const float* posB = pos + b*NELEC*3;

    // ---- wave roles ----
    // ee filter: waves 0-13 (t = w>=7), pair = (w mod 7)*64+lane -> SIMD (4,4,3,3)
    const int  ee_t   = (w >= 7) ? 1 : 0;
    const int  ee_p   = ((w >= 7 ? w - 7 : w) << 6) | lane;
    const bool ee_ok  = (w < 14) && (ee_p < NPEE);
    // en filter: active waves {0,1,2,3,4, 9,10,11,13,14} -> SIMD (2,3,3,2)
    const int  v      = w & 7;
    const int  en_blk = (w < 8) ? (v < 5 ? v : -1)
                                : ((v >= 1 && v <= 3) ? v - 1
                                   : (v == 5 || v == 6) ? v - 2 : -1);
    const int  en_t   = (w >= 8) ? 1 : 0;
    const int  en_p   = (en_blk < 0) ? 0 : ((en_blk << 6) | lane);
    const bool en_ok  = (en_blk >= 0) && (en_p < NPEN);
    // en h-init: waves {5,6,7,8,12} (disjoint from en-filter waves and w15)
    const int  hr     = (w == 5) ? 0 : (w == 6) ? 1 : (w == 7) ? 2
                      : (w == 8) ? 3 : (w == 12) ? 4 : -1;

    const int uoff_ee = __builtin_amdgcn_readfirstlane(ee_t * TILE);
    const int uoff_en = __builtin_amdgcn_readfirstlane(en_t * TILE);

    // ---------------- S0: ee filter (w0-13) || ee h0-init (w14-15) --------
    if (ee_ok) {
        int i = 0, rem = ee_p;
        while (rem >= NELEC - 1 - i) { rem -= NELEC - 1 - i; ++i; }
        const int j = i + 1 + rem;
        const float dx = posB[3*i+0] - posB[3*j+0];
        const float dy = posB[3*i+1] - posB[3*j+1];
        const float dz = posB[3*i+2] - posB[3*j+2];
        const float dd = sqrtf(dx*dx + dy*dy + dz*dz);
        rbf_filter(dd, wf_ee, bf_ee, uoff_ee, filt + ee_p*FPAD);
    }
    if (w >= 14) {   // 128 threads init h0 (1920 items, 15 iters)
        for (int idx = tid - 14*64; idx < NELEC*FEAT; idx += 128) {
            int n = idx >> 6, f = idx & 63;
            h0[idx] = emb_ee[ee_ty[n]*FEAT + f];
        }
    }
    __syncthreads();

    // ---------------- ee interaction layers (1 barrier each) --------------
    ee_layer(h0, h1, filt, wr, wl_ee + 0*FEAT*FEAT, bl_ee + 0*FEAT, w, lane);
    __syncthreads();
    ee_layer(h1, h0, filt, wr, wl_ee + 1*FEAT*FEAT, bl_ee + 1*FEAT, w, lane);
    __syncthreads();

    // ------- S3: ee readout (w15, h0) || en filter || en h1-init ----------
    if (en_ok) {
        const int a = en_p / NELEC;
        const int e = en_p - a*NELEC;
        const float dx = posB[3*e+0] - atoms[3*a+0];
        const float dy = posB[3*e+1] - atoms[3*a+1];
        const float dz = posB[3*e+2] - atoms[3*a+2];
        const float dd = sqrtf(dx*dx + dy*dy + dz*dz);
        rbf_filter(dd, wf_en, bf_en, uoff_en, filt + en_p*FPAD);
    }
    if (hr >= 0) {   // en h -> h1 (2560 items on 5 waves, 8 iters)
        #pragma unroll
        for (int r = 0; r < 8; ++r) {
            const int idx = hr*64 + lane + r*320;
            h1[idx] = emb_en[en_ty[idx >> 6]*FEAT + (idx & 63)];
        }
    }
    if (w == 15) {   // kee = (sum_n h0[n]) . wr + br  (f64 tail)
        float s = 0.f;
        #pragma unroll
        for (int n = 0; n < NELEC; ++n) s += h0[n*FEAT + lane];
        double dv = (double)s * (double)wr_ee[lane];
        #pragma unroll
        for (int o = 32; o > 0; o >>= 1) dv += __shfl_xor(dv, o, 64);
        if (lane == 0) *keeP = dv + (double)br_ee[0];
    }
    __syncthreads();

    // ---------------- en interaction layers -------------------------------
    en_layer(h1, h0, filt, wr, wl_en + 0*FEAT*FEAT, bl_en + 0*FEAT, w, lane);
    __syncthreads();
    en_layer(h0, h1, filt, wr, wl_en + 1*FEAT*FEAT, bl_en + 1*FEAT, w, lane);
    __syncthreads();

    // ---------------- final readout + combine -----------------------------
    if (w == 0) {
        float s = 0.f;
        #pragma unroll
        for (int n = 0; n < NNEN; ++n) s += h1[n*FEAT + lane];
        double dv = (double)s * (double)wr_en[lane];
        #pragma unroll
        for (int o = 32; o > 0; o >>= 1) dv += __shfl_xor(dv, o, 64);
        if (lane == 0) out[b] = (float)exp(dv + (double)br_en[0] + *keeP);
    }
}

// ==========================================================================
extern "C" void kernel_launch(void* const* d_in, const int* in_sizes, int n_in,
                              void* d_out, int out_size, void* d_ws, size_t ws_size,
                              hipStream_t stream) {
    const float* pos    = (const float*)d_in[0];
    const float* atoms  = (const float*)d_in[1];
    const float* emb_ee = (const float*)d_in[2];
    const float* wf_ee  = (const float*)d_in[3];
    const float* bf_ee  = (const float*)d_in[4];
    const float* wl_ee  = (const float*)d_in[5];
    const float* bl_ee  = (const float*)d_in[6];
    const float* wr_ee  = (const float*)d_in[7];
    const float* br_ee  = (const float*)d_in[8];
    const float* emb_en = (const float*)d_in[9];
    const float* wf_en  = (const float*)d_in[10];
    const float* bf_en  = (const float*)d_in[11];
    const float* wl_en  = (const float*)d_in[12];
    const float* bl_en  = (const float*)d_in[13];
    const float* wr_en  = (const float*)d_in[14];
    const float* br_en  = (const float*)d_in[15];
    const int*   ee_ty  = (const int*)d_in[18];
    const int*   en_ty  = (const int*)d_in[21];

    float* out = (float*)d_out;        // [512]

    (void)hipFuncSetAttribute((const void*)fused_kernel,
            hipFuncAttributeMaxDynamicSharedMemorySize, SM_TOTAL*(int)sizeof(float));

    fused_kernel<<<NB, BLOCK, SM_TOTAL*sizeof(float), stream>>>(
        pos, atoms,
        emb_ee, wf_ee, bf_ee, wl_ee, bl_ee, wr_ee, br_ee,
        emb_en, wf_en, bf_en, wl_en, bl_en, wr_en, br_en,
        ee_ty, en_ty, out);
}